// Round 16
// baseline (187.277 us; speedup 1.0000x reference)
//
#include <hip/hip_runtime.h>

#define NHEADS 16
#define DEPTH  64
#define BATCH  8
#define SEQ    1024
#define DMODEL 1024
#define MTOT   (BATCH*SEQ)   // 8192

typedef float f32x4 __attribute__((ext_vector_type(4)));
typedef int   i32x4 __attribute__((ext_vector_type(4)));
typedef unsigned short u16;

static __device__ inline u16 f2bf(float x) {
    unsigned int u = __builtin_bit_cast(unsigned int, x);
    u += 0x7FFFu + ((u >> 16) & 1u);   // RNE
    return (u16)(u >> 16);
}

// pack 2 f32 -> 2 bf16 (RNE), one instruction; lo -> low 16 bits (r10-proven)
static __device__ inline unsigned cvt_pk_bf16(float lo, float hi) {
    unsigned r;
    asm("v_cvt_pk_bf16_f32 %0, %1, %2" : "=v"(r) : "v"(lo), "v"(hi));
    return r;
}

// D = A(16x32, bf16) * B(32x16, bf16) + D, fp32 acc.
// A frag: lane holds A[l&15][8*(l>>4)+i] ; B frag: B[8*(l>>4)+i][l&15]
// C/D:    lane,reg r -> D[(l>>4)*4 + r][l&15]
static __device__ inline void mfma_bf16(f32x4& acc, i32x4 a, i32x4 b) {
    asm("v_mfma_f32_16x16x32_bf16 %0, %1, %2, %0" : "+v"(acc) : "v"(a), "v"(b));
}

// async global->LDS, 16B/lane; lds dest is wave-uniform base (+ lane*16 by HW)
static __device__ inline void gload16(const u16* g, u16* l) {
    __builtin_amdgcn_global_load_lds(
        (const __attribute__((address_space(1))) void*)g,
        (__attribute__((address_space(3))) void*)l,
        16, 0, 0);
}

// ---------------- fp32 -> bf16 convert (streaming) ----------------
__global__ __launch_bounds__(256) void cvt_kernel(
    const float* __restrict__ A, const float* __restrict__ B, const float* __restrict__ C,
    u16* __restrict__ Ao, u16* __restrict__ Bo, u16* __restrict__ Co)
{
    const float* src = (blockIdx.y == 0) ? A : (blockIdx.y == 1) ? B : C;
    u16* dst         = (blockIdx.y == 0) ? Ao : (blockIdx.y == 1) ? Bo : Co;
    int i = (blockIdx.x * 256 + threadIdx.x) * 8;
    float4 f0 = *reinterpret_cast<const float4*>(src + i);
    float4 f1 = *reinterpret_cast<const float4*>(src + i + 4);
    uint4 u;
    u.x = cvt_pk_bf16(f0.x, f0.y);
    u.y = cvt_pk_bf16(f0.z, f0.w);
    u.z = cvt_pk_bf16(f1.x, f1.y);
    u.w = cvt_pk_bf16(f1.z, f1.w);
    *reinterpret_cast<uint4*>(dst + i) = u;
}

// ---------------- weight transpose + fp32->bf16 convert ----------------
// Wt[n][k] = bf16(W[k][n]); W is K x N row-major fp32.
__global__ __launch_bounds__(256) void transpose_cvt_kernel(
    const float* __restrict__ W, u16* __restrict__ Wt, int K, int N)
{
    __shared__ u16 tile[32][33];
    int n0 = blockIdx.x * 32, k0 = blockIdx.y * 32;
    int tx = threadIdx.x & 31, ty = threadIdx.x >> 5;   // 32 x 8
    #pragma unroll
    for (int r = 0; r < 32; r += 8)
        tile[r + ty][tx] = f2bf(W[(k0 + r + ty) * N + n0 + tx]);
    __syncthreads();
    #pragma unroll
    for (int r = 0; r < 32; r += 8)
        Wt[(n0 + r + ty) * K + k0 + tx] = tile[tx][r + ty];
}

// ---------------- QKV projection: 2-phase dbuf pipeline (r15-outproj-proven structure) ----------------
// BK=64, gload both sides, source-swizzled LDS, double-buffered, one barrier/K-step.
__global__ __launch_bounds__(256) void proj_kernel(
    const u16* __restrict__ Xq, const u16* __restrict__ Xk, const u16* __restrict__ Xv,
    const u16* __restrict__ Wtq, const u16* __restrict__ Wtk, const u16* __restrict__ Wtv,
    const float* __restrict__ Bq, const float* __restrict__ Bk, const float* __restrict__ Bv,
    u16* __restrict__ Qh, u16* __restrict__ Kh, u16* __restrict__ Vt)
{
    const int z = blockIdx.z;
    const u16* X    = (z == 0) ? Xq  : (z == 1) ? Xk  : Xv;
    const u16* Wt   = (z == 0) ? Wtq : (z == 1) ? Wtk : Wtv;
    const float* Bi = (z == 0) ? Bq  : (z == 1) ? Bk  : Bv;
    u16* Out        = (z == 0) ? Qh  : (z == 1) ? Kh  : Vt;

    __shared__ u16 As[2][128 * 64];
    __shared__ u16 Bs[2][128 * 64];

    const int t = threadIdx.x;
    const int m0 = blockIdx.x * 128, n0 = blockIdx.y * 128;
    const int lane = t & 63, w = t >> 6;
    const int wu = __builtin_amdgcn_readfirstlane(w);
    const int wm = w >> 1, wn = w & 1;
    const int lr = lane & 15, lg = lane >> 4;
    const int srow = lane >> 3;                              // 8 rows per gload
    const int scol = ((lane & 7) ^ (srow & 7)) * 8;          // pre-swizzled source slot

    const u16* ga = X  + (m0 + wu * 32 + srow) * DMODEL + scol;
    const u16* gb = Wt + (n0 + wu * 32 + srow) * DMODEL + scol;

    f32x4 acc[4][4];
    #pragma unroll
    for (int i = 0; i < 4; ++i)
        #pragma unroll
        for (int j = 0; j < 4; ++j) acc[i][j] = f32x4{0.f, 0.f, 0.f, 0.f};

    auto STAGE = [&](int buf, int k0) {
        u16* la = As[buf] + wu * 32 * 64;
        u16* lb = Bs[buf] + wu * 32 * 64;
        gload16(ga + k0,               la);
        gload16(ga + k0 +  8 * DMODEL, la +  8 * 64);   // row += 8: row&7 unchanged
        gload16(ga + k0 + 16 * DMODEL, la + 16 * 64);
        gload16(ga + k0 + 24 * DMODEL, la + 24 * 64);
        gload16(gb + k0,               lb);
        gload16(gb + k0 +  8 * DMODEL, lb +  8 * 64);
        gload16(gb + k0 + 16 * DMODEL, lb + 16 * 64);
        gload16(gb + k0 + 24 * DMODEL, lb + 24 * 64);
    };

    STAGE(0, 0);
    __syncthreads();   // drain prologue stage
    for (int ts = 0; ts < 16; ++ts) {
        if (ts < 15) STAGE((ts + 1) & 1, (ts + 1) * 64);   // issue next tile early
        const u16* Ac = As[ts & 1];
        const u16* Bc = Bs[ts & 1];
        #pragma unroll
        for (int kk = 0; kk < 2; ++kk) {
            const int pslot = ((kk * 4 + lg) ^ (lr & 7)) << 3;   // swizzled read slot
            i32x4 af[4], bfr[4];
            #pragma unroll
            for (int mi = 0; mi < 4; ++mi)
                af[mi] = *reinterpret_cast<const i32x4*>(
                    &Ac[(wm * 64 + mi * 16 + lr) * 64 + pslot]);
            #pragma unroll
            for (int ni = 0; ni < 4; ++ni)
                bfr[ni] = *reinterpret_cast<const i32x4*>(
                    &Bc[(wn * 64 + ni * 16 + lr) * 64 + pslot]);
            #pragma unroll
            for (int mi = 0; mi < 4; ++mi)
                #pragma unroll
                for (int ni = 0; ni < 4; ++ni)
                    mfma_bf16(acc[mi][ni], af[mi], bfr[ni]);
        }
        __syncthreads();   // drains next-stage loads (flew during compute) + reads done
    }
    asm volatile("s_nop 7\n\ts_nop 7");
    #pragma unroll
    for (int mi = 0; mi < 4; ++mi)
        #pragma unroll
        for (int ni = 0; ni < 4; ++ni) {
            int n = n0 + wn * 64 + ni * 16 + lr;
            float bv = Bi[n];
            int h = n >> 6, d = n & 63;
            int mb = m0 + wm * 64 + mi * 16 + lg * 4;
            int b = mb >> 10, srw = mb & 1023;
            if (z == 2) {
                uint2 u;
                u.x = cvt_pk_bf16(acc[mi][ni][0] + bv, acc[mi][ni][1] + bv);
                u.y = cvt_pk_bf16(acc[mi][ni][2] + bv, acc[mi][ni][3] + bv);
                *reinterpret_cast<uint2*>(&Vt[(((b << 4) + h) * DEPTH + d) * SEQ + srw]) = u;
            } else if (z == 0) {
                // 0.125 (1/sqrt(64)) * log2(e): scores come out of QK^T in exp2 domain
                #pragma unroll
                for (int r = 0; r < 4; ++r)
                    Out[(((b << 4) + h) * SEQ + srw + r) * DEPTH + d] = f2bf((acc[mi][ni][r] + bv) * 0.18033688f);
            } else {
                #pragma unroll
                for (int r = 0; r < 4; ++r)
                    Out[(((b << 4) + h) * SEQ + srw + r) * DEPTH + d] = f2bf(acc[mi][ni][r] + bv);
            }
        }
}

// ---------------- flash attention (r15-proven; + T5 setprio around MFMA clusters) ----------------
__global__ __launch_bounds__(256) void attn_kernel(
    u16* __restrict__ Qh, const u16* __restrict__ Kh, const u16* __restrict__ Vt,
    const float* __restrict__ mask)
{
    __shared__ u16 Ks[64 * 64];
    __shared__ u16 Vts[64 * 64];     // [d][k]
    __shared__ u16 Ps[4][32 * 64];   // per-wave [32 q][64 k], swizzled cols
    __shared__ float Ms[SEQ];

    const int t = threadIdx.x;
    const int lane = t & 63, w = t >> 6;
    const int lr = lane & 15, lg = lane >> 4;
    const int bh = blockIdx.y;
    const int b = bh >> 4;
    const int qw = blockIdx.x * 128 + w * 32;   // this wave's 32 q rows

    u16* Qp       = Qh + bh * (SEQ * DEPTH);
    const u16* Kp = Kh + bh * (SEQ * DEPTH);
    const u16* Vp = Vt + bh * (SEQ * DEPTH);   // [d][s]

    // stage mask * (-1e9 * log2e) once (visible after first loop barrier)
    {
        float4 mv = *reinterpret_cast<const float4*>(mask + b * SEQ + t * 4);
        const float mk = -1.4426950408889634e9f;
        Ms[t * 4 + 0] = mv.x * mk;
        Ms[t * 4 + 1] = mv.y * mk;
        Ms[t * 4 + 2] = mv.z * mk;
        Ms[t * 4 + 3] = mv.w * mk;
    }

    i32x4 aq[2][2];   // [q-group][k-half]
    #pragma unroll
    for (int g = 0; g < 2; ++g) {
        aq[g][0] = *reinterpret_cast<const i32x4*>(&Qp[(qw + g * 16 + lr) * DEPTH + lg * 8]);
        aq[g][1] = *reinterpret_cast<const i32x4*>(&Qp[(qw + g * 16 + lr) * DEPTH + 32 + lg * 8]);
    }

    f32x4 ctx[2][4];
    #pragma unroll
    for (int g = 0; g < 2; ++g)
        #pragma unroll
        for (int i = 0; i < 4; ++i) ctx[g][i] = f32x4{0.f, 0.f, 0.f, 0.f};
    float psum[2] = {0.f, 0.f};

    // staging geometry: row r0 (0..31), 16B slot c8 (0..7), swizzle slot ^= row&7
    const int r0 = t >> 3;
    const int c8 = t & 7;
    const int swz0 = (c8 ^ (r0 & 7)) * 8;   // (r0+32)&7 == r0&7
    u16* kd0 = Ks  + r0 * 64 + swz0;
    u16* kd1 = Ks  + (r0 + 32) * 64 + swz0;
    u16* vd0 = Vts + r0 * 64 + swz0;
    u16* vd1 = Vts + (r0 + 32) * 64 + swz0;
    const u16* ksrc0 = Kp + r0 * DEPTH + c8 * 8;
    const u16* ksrc1 = Kp + (r0 + 32) * DEPTH + c8 * 8;
    const u16* vsrc0 = Vp + r0 * SEQ + c8 * 8;
    const u16* vsrc1 = Vp + (r0 + 32) * SEQ + c8 * 8;
    u16* PsW = Ps[w];

    // loop-invariant P-store pointers: row q = g*16+lr, k-cols tt*16 + lg*4 .. +3
    u16* pdst[2][4];
    #pragma unroll
    for (int g = 0; g < 2; ++g)
        #pragma unroll
        for (int tt = 0; tt < 4; ++tt) {
            int slot = tt * 2 + (lg >> 1);
            pdst[g][tt] = PsW + (g * 16 + lr) * 64 + ((slot ^ (lr & 7)) << 3) + ((lg & 1) << 2);
        }

    // T14: prime first tile into registers
    uint4 kr0 = *reinterpret_cast<const uint4*>(ksrc0);
    uint4 kr1 = *reinterpret_cast<const uint4*>(ksrc1);
    uint4 vr0 = *reinterpret_cast<const uint4*>(vsrc0);
    uint4 vr1 = *reinterpret_cast<const uint4*>(vsrc1);

    for (int kt = 0; kt < SEQ; kt += 64) {
        __syncthreads();   // previous tile's compute done; LDS free
        *reinterpret_cast<uint4*>(kd0) = kr0;
        *reinterpret_cast<uint4*>(kd1) = kr1;
        *reinterpret_cast<uint4*>(vd0) = vr0;
        *reinterpret_cast<uint4*>(vd1) = vr1;
        if (kt + 64 < SEQ) {   // issue next tile's loads; complete under compute
            int kn = kt + 64;
            kr0 = *reinterpret_cast<const uint4*>(ksrc0 + kn * DEPTH);
            kr1 = *reinterpret_cast<const uint4*>(ksrc1 + kn * DEPTH);
            vr0 = *reinterpret_cast<const uint4*>(vsrc0 + kn);
            vr1 = *reinterpret_cast<const uint4*>(vsrc1 + kn);
        }
        __syncthreads();

        // QK^T, swapped operands: lane holds q = g*16+lr, k = tt*16+lg*4+r
        f32x4 sc[2][4];
        #pragma unroll
        for (int g = 0; g < 2; ++g)
            #pragma unroll
            for (int i = 0; i < 4; ++i) sc[g][i] = f32x4{0.f, 0.f, 0.f, 0.f};
        __builtin_amdgcn_s_setprio(1);
        #pragma unroll
        for (int tt = 0; tt < 4; ++tt) {
            int row = tt * 16 + lr, rs = row & 7;
            const u16* kr = Ks + row * 64;
            i32x4 bk0 = *reinterpret_cast<const i32x4*>(kr + ((lg ^ rs) << 3));
            i32x4 bk1 = *reinterpret_cast<const i32x4*>(kr + (((4 + lg) ^ rs) << 3));
            mfma_bf16(sc[0][tt], bk0, aq[0][0]);
            mfma_bf16(sc[0][tt], bk1, aq[0][1]);
            mfma_bf16(sc[1][tt], bk0, aq[1][0]);
            mfma_bf16(sc[1][tt], bk1, aq[1][1]);
        }
        __builtin_amdgcn_s_setprio(0);
        asm volatile("s_nop 7\n\ts_nop 7");

        #pragma unroll
        for (int tt = 0; tt < 4; ++tt) {
            float4 m4 = *reinterpret_cast<const float4*>(&Ms[kt + tt * 16 + lg * 4]);
            #pragma unroll
            for (int g = 0; g < 2; ++g) {
                float p0 = __builtin_amdgcn_exp2f(sc[g][tt][0] + m4.x);
                float p1 = __builtin_amdgcn_exp2f(sc[g][tt][1] + m4.y);
                float p2 = __builtin_amdgcn_exp2f(sc[g][tt][2] + m4.z);
                float p3 = __builtin_amdgcn_exp2f(sc[g][tt][3] + m4.w);
                psum[g] += (p0 + p1) + (p2 + p3);
                uint2 u;
                u.x = cvt_pk_bf16(p0, p1);
                u.y = cvt_pk_bf16(p2, p3);
                *reinterpret_cast<uint2*>(pdst[g][tt]) = u;
            }
        }

        // PV: ctx[g](16q x 64d) += P[g](16q x 64k) @ V(64k x 64d); bv shared across groups
        const int rswz = lr & 7;
        i32x4 pa[2][2];
        #pragma unroll
        for (int g = 0; g < 2; ++g) {
            const u16* pr = PsW + (g * 16 + lr) * 64;
            pa[g][0] = *reinterpret_cast<const i32x4*>(pr + ((lg ^ rswz) << 3));
            pa[g][1] = *reinterpret_cast<const i32x4*>(pr + (((4 + lg) ^ rswz) << 3));
        }
        __builtin_amdgcn_s_setprio(1);
        #pragma unroll
        for (int dt = 0; dt < 4; ++dt) {
            int dcol = dt * 16 + lr, ds = dcol & 7;
            const u16* vr = Vts + dcol * 64;
            i32x4 bv0 = *reinterpret_cast<const i32x4*>(vr + ((lg ^ ds) << 3));
            i32x4 bv1 = *reinterpret_cast<const i32x4*>(vr + (((4 + lg) ^ ds) << 3));
            mfma_bf16(ctx[0][dt], pa[0][0], bv0);
            mfma_bf16(ctx[0][dt], pa[0][1], bv1);
            mfma_bf16(ctx[1][dt], pa[1][0], bv0);
            mfma_bf16(ctx[1][dt], pa[1][1], bv1);
        }
        __builtin_amdgcn_s_setprio(0);
    }
    asm volatile("s_nop 7\n\ts_nop 7");
    #pragma unroll
    for (int g = 0; g < 2; ++g) {
        psum[g] += __shfl_xor(psum[g], 16);
        psum[g] += __shfl_xor(psum[g], 32);
    }
    float inv0 = 1.f / psum[0];
    float inv1 = 1.f / psum[1];
    // in-place ctx write over this wave's own Q rows (head layout)
    #pragma unroll
    for (int g = 0; g < 2; ++g) {
        float invr[4];
        #pragma unroll
        for (int r = 0; r < 4; ++r)
            invr[r] = __shfl(g ? inv1 : inv0, lg * 4 + r);   // ctx rows q = g*16 + lg*4 + r
        #pragma unroll
        for (int dt = 0; dt < 4; ++dt)
            #pragma unroll
            for (int r = 0; r < 4; ++r) {
                int s = qw + g * 16 + lg * 4 + r;
                int d = dt * 16 + lr;
                Qp[s * DEPTH + d] = f2bf(ctx[g][dt][r] * invr[r]);
            }
    }
}

// ---------------- output projection (r15-proven, verbatim: 2-phase, all-gload) ----------------
__global__ __launch_bounds__(256) void outproj_kernel(
    const u16* __restrict__ Xbq, const u16* __restrict__ CTXh,
    const u16* __restrict__ Wto,  // bf16 (1024 n x 2048 k)
    const float* __restrict__ Bo, float* __restrict__ Out)
{
    __shared__ u16 As[2][128 * 64];
    __shared__ u16 Bs[2][128 * 64];

    const int t = threadIdx.x;
    const int m0 = blockIdx.x * 128, n0 = blockIdx.y * 128;
    const int lane = t & 63, w = t >> 6;
    const int wu = __builtin_amdgcn_readfirstlane(w);
    const int wm = w >> 1, wn = w & 1;
    const int lr = lane & 15, lg = lane >> 4;
    const int srow = lane >> 3;                              // 8 rows per gload
    const int scol = ((lane & 7) ^ (srow & 7)) * 8;          // pre-swizzled source slot

    const int rowslab = m0 + wu * 32;                        // slab base row
    const int bb = rowslab >> 10, sr = rowslab & 1023;       // batch, seq base
    const u16* gaq = Xbq + (rowslab + srow) * DMODEL + scol;
    const u16* gb  = Wto + (n0 + wu * 32 + srow) * (2 * DMODEL) + scol;

    f32x4 acc[4][4];
    #pragma unroll
    for (int i = 0; i < 4; ++i)
        #pragma unroll
        for (int j = 0; j < 4; ++j) acc[i][j] = f32x4{0.f, 0.f, 0.f, 0.f};

    auto STAGE = [&](int buf, int k0) {
        u16* la = As[buf] + wu * 32 * 64;
        u16* lb = Bs[buf] + wu * 32 * 64;
        gload16(gb + k0,                   lb);
        gload16(gb + k0 +  8 * 2 * DMODEL, lb +  8 * 64);   // row += 8: row&7 unchanged
        gload16(gb + k0 + 16 * 2 * DMODEL, lb + 16 * 64);
        gload16(gb + k0 + 24 * 2 * DMODEL, lb + 24 * 64);
        const u16* ga;
        int rstride;
        if (k0 < DMODEL) {
            ga = gaq + k0;
            rstride = DMODEL;
        } else {
            int h = (k0 - DMODEL) >> 6;
            ga = CTXh + (((bb << 4) + h) * SEQ + sr + srow) * DEPTH + scol;
            rstride = DEPTH;
        }
        gload16(ga,                la);
        gload16(ga +  8 * rstride, la +  8 * 64);
        gload16(ga + 16 * rstride, la + 16 * 64);
        gload16(ga + 24 * rstride, la + 24 * 64);
    };

    STAGE(0, 0);
    __syncthreads();   // drain prologue stage
    for (int ts = 0; ts < 32; ++ts) {
        if (ts < 31) STAGE((ts + 1) & 1, (ts + 1) * 64);   // issue next tile early
        const int cur = ts & 1;
        const u16* Ac = As[cur];
        const u16* Bc = Bs[cur];
        #pragma unroll
        for (int kk = 0; kk < 2; ++kk) {
            const int pslot = ((kk * 4 + lg) ^ (lr & 7)) << 3;   // swizzled read slot
            i32x4 af[4], bfr[4];
            #pragma unroll
            for (int mi = 0; mi < 4; ++mi)
                af[mi] = *reinterpret_cast<const i32x4*>(
                    &Ac[(wm * 64 + mi * 16 + lr) * 64 + pslot]);
            #pragma unroll
            for (int ni = 0; ni < 4; ++ni)
                bfr[ni] = *reinterpret_cast<const i32x4*>(
                    &Bc[(wn * 64 + ni * 16 + lr) * 64 + pslot]);
            #pragma unroll
            for (int mi = 0; mi < 4; ++mi)
                #pragma unroll
                for (int ni = 0; ni < 4; ++ni)
                    mfma_bf16(acc[mi][ni], af[mi], bfr[ni]);
        }
        __syncthreads();   // drains stage(ts+1) loads (flew during compute)
    }
    asm volatile("s_nop 7\n\ts_nop 7");
    #pragma unroll
    for (int mi = 0; mi < 4; ++mi)
        #pragma unroll
        for (int ni = 0; ni < 4; ++ni) {
            int n = n0 + wn * 64 + ni * 16 + lr;
            float bv = Bo[n];
            #pragma unroll
            for (int r = 0; r < 4; ++r) {
                int m = m0 + wm * 64 + mi * 16 + lg * 4 + r;
                Out[m * DMODEL + n] = acc[mi][ni][r] + bv;
            }
        }
}

extern "C" void kernel_launch(void* const* d_in, const int* in_sizes, int n_in,
                              void* d_out, int out_size, void* d_ws, size_t ws_size,
                              hipStream_t stream) {
    const float* v    = (const float*)d_in[0];
    const float* k    = (const float*)d_in[1];
    const float* q_in = (const float*)d_in[2];
    const float* mask = (const float*)d_in[3];
    const float* wq_w = (const float*)d_in[4];
    const float* wq_b = (const float*)d_in[5];
    const float* wk_w = (const float*)d_in[6];
    const float* wk_b = (const float*)d_in[7];
    const float* wv_w = (const float*)d_in[8];
    const float* wv_b = (const float*)d_in[9];
    const float* wo_w = (const float*)d_in[10];
    const float* wo_b = (const float*)d_in[11];
    float* out = (float*)d_out;

    // proven 74 MB workspace layout
    u16* ws  = (u16*)d_ws;
    u16* Wtq = ws;                  // 1M u16
    u16* Wtk = Wtq + (1u << 20);
    u16* Wtv = Wtk + (1u << 20);
    u16* Wto = Wtv + (1u << 20);    // 2M u16
    u16* Qh  = Wto + (2u << 20);    // 8M u16 each: Qh -> ctx in-place
    u16* Kh  = Qh + (8u << 20);
    u16* Vt  = Kh + (8u << 20);     // transposed (B,H,64,S)
    u16* Xbq = Vt + (8u << 20);     // bf16 q_in, live until outproj

    // bf16 k/v scratch in d_out (dead before outproj writes out)
    u16* Xbk = (u16*)d_out;
    u16* Xbv = (u16*)d_out + (8u << 20);

    cvt_kernel<<<dim3(4096, 3), 256, 0, stream>>>(q_in, k, v, Xbq, Xbk, Xbv);

    transpose_cvt_kernel<<<dim3(32, 32), 256, 0, stream>>>(wq_w, Wtq, 1024, 1024);
    transpose_cvt_kernel<<<dim3(32, 32), 256, 0, stream>>>(wk_w, Wtk, 1024, 1024);
    transpose_cvt_kernel<<<dim3(32, 32), 256, 0, stream>>>(wv_w, Wtv, 1024, 1024);
    transpose_cvt_kernel<<<dim3(32, 64), 256, 0, stream>>>(wo_w, Wto, 2048, 1024);

    proj_kernel<<<dim3(64, 8, 3), 256, 0, stream>>>(
        Xbq, Xbk, Xbv, Wtq, Wtk, Wtv, wq_b, wk_b, wv_b, Qh, Kh, Vt);

    attn_kernel<<<dim3(8, 128), 256, 0, stream>>>(Qh, Kh, Vt, mask);

    outproj_kernel<<<dim3(64, 8), 256, 0, stream>>>(Xbq, Qh, Wto, wo_b, out);
}

// Round 17
// 174.217 us; speedup vs baseline: 1.0750x; 1.0750x over previous
//
#include <hip/hip_runtime.h>

#define NHEADS 16
#define DEPTH  64
#define BATCH  8
#define SEQ    1024
#define DMODEL 1024
#define MTOT   (BATCH*SEQ)   // 8192

typedef float f32x4 __attribute__((ext_vector_type(4)));
typedef int   i32x4 __attribute__((ext_vector_type(4)));
typedef unsigned short u16;

static __device__ inline u16 f2bf(float x) {
    unsigned int u = __builtin_bit_cast(unsigned int, x);
    u += 0x7FFFu + ((u >> 16) & 1u);   // RNE
    return (u16)(u >> 16);
}

// pack 2 f32 -> 2 bf16 (RNE), one instruction; lo -> low 16 bits (r10-proven)
static __device__ inline unsigned cvt_pk_bf16(float lo, float hi) {
    unsigned r;
    asm("v_cvt_pk_bf16_f32 %0, %1, %2" : "=v"(r) : "v"(lo), "v"(hi));
    return r;
}

// D = A(16x32, bf16) * B(32x16, bf16) + D, fp32 acc.
// A frag: lane holds A[l&15][8*(l>>4)+i] ; B frag: B[8*(l>>4)+i][l&15]
// C/D:    lane,reg r -> D[(l>>4)*4 + r][l&15]
static __device__ inline void mfma_bf16(f32x4& acc, i32x4 a, i32x4 b) {
    asm("v_mfma_f32_16x16x32_bf16 %0, %1, %2, %0" : "+v"(acc) : "v"(a), "v"(b));
}

// async global->LDS, 16B/lane; lds dest is wave-uniform base (+ lane*16 by HW)
static __device__ inline void gload16(const u16* g, u16* l) {
    __builtin_amdgcn_global_load_lds(
        (const __attribute__((address_space(1))) void*)g,
        (__attribute__((address_space(3))) void*)l,
        16, 0, 0);
}

// ---------------- fp32 -> bf16 convert (streaming) ----------------
__global__ __launch_bounds__(256) void cvt_kernel(
    const float* __restrict__ A, const float* __restrict__ B, const float* __restrict__ C,
    u16* __restrict__ Ao, u16* __restrict__ Bo, u16* __restrict__ Co)
{
    const float* src = (blockIdx.y == 0) ? A : (blockIdx.y == 1) ? B : C;
    u16* dst         = (blockIdx.y == 0) ? Ao : (blockIdx.y == 1) ? Bo : Co;
    int i = (blockIdx.x * 256 + threadIdx.x) * 8;
    float4 f0 = *reinterpret_cast<const float4*>(src + i);
    float4 f1 = *reinterpret_cast<const float4*>(src + i + 4);
    uint4 u;
    u.x = cvt_pk_bf16(f0.x, f0.y);
    u.y = cvt_pk_bf16(f0.z, f0.w);
    u.z = cvt_pk_bf16(f1.x, f1.y);
    u.w = cvt_pk_bf16(f1.z, f1.w);
    *reinterpret_cast<uint4*>(dst + i) = u;
}

// ---------------- weight transpose + fp32->bf16 convert (single launch, z-indexed) ----------------
// z in {0,1,2}: 1024x1024 (wq,wk,wv); z=3: 2048x1024 (wo). Wt[n][k] = bf16(W[k][n]).
__global__ __launch_bounds__(256) void transpose_cvt_all(
    const float* __restrict__ Wq, const float* __restrict__ Wk,
    const float* __restrict__ Wv, const float* __restrict__ Wo,
    u16* __restrict__ Wtq, u16* __restrict__ Wtk,
    u16* __restrict__ Wtv, u16* __restrict__ Wto)
{
    const int z = blockIdx.z;
    if (z < 3 && blockIdx.y >= 32) return;
    const float* W = (z == 0) ? Wq : (z == 1) ? Wk : (z == 2) ? Wv : Wo;
    u16* Wt        = (z == 0) ? Wtq : (z == 1) ? Wtk : (z == 2) ? Wtv : Wto;
    const int K = (z == 3) ? 2048 : 1024;
    const int N = 1024;

    __shared__ u16 tile[32][33];
    int n0 = blockIdx.x * 32, k0 = blockIdx.y * 32;
    int tx = threadIdx.x & 31, ty = threadIdx.x >> 5;   // 32 x 8
    #pragma unroll
    for (int r = 0; r < 32; r += 8)
        tile[r + ty][tx] = f2bf(W[(k0 + r + ty) * N + n0 + tx]);
    __syncthreads();
    #pragma unroll
    for (int r = 0; r < 32; r += 8)
        Wt[(n0 + r + ty) * K + k0 + tx] = tile[tx][r + ty];
}

// ---------------- QKV projection (r15-proven: single-buffer BK=64, source-swizzled LDS) ----------------
// 32 KB LDS -> high occupancy; wave-level overlap beats dbuf here (r16 lesson).
__global__ __launch_bounds__(256) void proj_kernel(
    const u16* __restrict__ Xq, const u16* __restrict__ Xk, const u16* __restrict__ Xv,
    const u16* __restrict__ Wtq, const u16* __restrict__ Wtk, const u16* __restrict__ Wtv,
    const float* __restrict__ Bq, const float* __restrict__ Bk, const float* __restrict__ Bv,
    u16* __restrict__ Qh, u16* __restrict__ Kh, u16* __restrict__ Vt)
{
    const int z = blockIdx.z;
    const u16* X    = (z == 0) ? Xq  : (z == 1) ? Xk  : Xv;
    const u16* Wt   = (z == 0) ? Wtq : (z == 1) ? Wtk : Wtv;
    const float* Bi = (z == 0) ? Bq  : (z == 1) ? Bk  : Bv;
    u16* Out        = (z == 0) ? Qh  : (z == 1) ? Kh  : Vt;

    __shared__ u16 As[128 * 64];
    __shared__ u16 Bs[128 * 64];

    const int t = threadIdx.x;
    const int m0 = blockIdx.x * 128, n0 = blockIdx.y * 128;
    const int lane = t & 63, w = t >> 6;
    const int wu = __builtin_amdgcn_readfirstlane(w);
    const int wm = w >> 1, wn = w & 1;
    const int lr = lane & 15, lg = lane >> 4;
    const int srow = lane >> 3;                              // 8 rows per gload
    const int scol = ((lane & 7) ^ (srow & 7)) * 8;          // pre-swizzled source slot

    const u16* ga = X  + (m0 + wu * 32 + srow) * DMODEL + scol;
    const u16* gb = Wt + (n0 + wu * 32 + srow) * DMODEL + scol;
    u16* la = As + wu * 32 * 64;
    u16* lb = Bs + wu * 32 * 64;

    f32x4 acc[4][4];
    #pragma unroll
    for (int i = 0; i < 4; ++i)
        #pragma unroll
        for (int j = 0; j < 4; ++j) acc[i][j] = f32x4{0.f, 0.f, 0.f, 0.f};

    for (int k0 = 0; k0 < DMODEL; k0 += 64) {
        __syncthreads();
        gload16(ga + k0,               la);
        gload16(ga + k0 +  8 * DMODEL, la +  8 * 64);   // row += 8: row&7 unchanged
        gload16(ga + k0 + 16 * DMODEL, la + 16 * 64);
        gload16(ga + k0 + 24 * DMODEL, la + 24 * 64);
        gload16(gb + k0,               lb);
        gload16(gb + k0 +  8 * DMODEL, lb +  8 * 64);
        gload16(gb + k0 + 16 * DMODEL, lb + 16 * 64);
        gload16(gb + k0 + 24 * DMODEL, lb + 24 * 64);
        __syncthreads();
        #pragma unroll
        for (int kk = 0; kk < 2; ++kk) {
            const int pslot = ((kk * 4 + lg) ^ (lr & 7)) << 3;   // swizzled read slot
            i32x4 af[4], bfr[4];
            #pragma unroll
            for (int mi = 0; mi < 4; ++mi)
                af[mi] = *reinterpret_cast<const i32x4*>(
                    &As[(wm * 64 + mi * 16 + lr) * 64 + pslot]);
            #pragma unroll
            for (int ni = 0; ni < 4; ++ni)
                bfr[ni] = *reinterpret_cast<const i32x4*>(
                    &Bs[(wn * 64 + ni * 16 + lr) * 64 + pslot]);
            #pragma unroll
            for (int mi = 0; mi < 4; ++mi)
                #pragma unroll
                for (int ni = 0; ni < 4; ++ni)
                    mfma_bf16(acc[mi][ni], af[mi], bfr[ni]);
        }
    }
    asm volatile("s_nop 7\n\ts_nop 7");
    #pragma unroll
    for (int mi = 0; mi < 4; ++mi)
        #pragma unroll
        for (int ni = 0; ni < 4; ++ni) {
            int n = n0 + wn * 64 + ni * 16 + lr;
            float bv = Bi[n];
            int h = n >> 6, d = n & 63;
            int mb = m0 + wm * 64 + mi * 16 + lg * 4;
            int b = mb >> 10, srw = mb & 1023;
            if (z == 2) {
                uint2 u;
                u.x = cvt_pk_bf16(acc[mi][ni][0] + bv, acc[mi][ni][1] + bv);
                u.y = cvt_pk_bf16(acc[mi][ni][2] + bv, acc[mi][ni][3] + bv);
                *reinterpret_cast<uint2*>(&Vt[(((b << 4) + h) * DEPTH + d) * SEQ + srw]) = u;
            } else if (z == 0) {
                // 0.125 (1/sqrt(64)) * log2(e): scores come out of QK^T in exp2 domain
                #pragma unroll
                for (int r = 0; r < 4; ++r)
                    Out[(((b << 4) + h) * SEQ + srw + r) * DEPTH + d] = f2bf((acc[mi][ni][r] + bv) * 0.18033688f);
            } else {
                #pragma unroll
                for (int r = 0; r < 4; ++r)
                    Out[(((b << 4) + h) * SEQ + srw + r) * DEPTH + d] = f2bf(acc[mi][ni][r] + bv);
            }
        }
}

// ---------------- flash attention (r15-proven; ctx in-place over Q; setprio on MFMA) ----------------
__global__ __launch_bounds__(256) void attn_kernel(
    u16* __restrict__ Qh, const u16* __restrict__ Kh, const u16* __restrict__ Vt,
    const float* __restrict__ mask)
{
    __shared__ u16 Ks[64 * 64];
    __shared__ u16 Vts[64 * 64];     // [d][k]
    __shared__ u16 Ps[4][32 * 64];   // per-wave [32 q][64 k], swizzled cols
    __shared__ float Ms[SEQ];

    const int t = threadIdx.x;
    const int lane = t & 63, w = t >> 6;
    const int lr = lane & 15, lg = lane >> 4;
    const int bh = blockIdx.y;
    const int b = bh >> 4;
    const int qw = blockIdx.x * 128 + w * 32;   // this wave's 32 q rows

    u16* Qp       = Qh + bh * (SEQ * DEPTH);
    const u16* Kp = Kh + bh * (SEQ * DEPTH);
    const u16* Vp = Vt + bh * (SEQ * DEPTH);   // [d][s]

    // stage mask * (-1e9 * log2e) once (visible after first loop barrier)
    {
        float4 mv = *reinterpret_cast<const float4*>(mask + b * SEQ + t * 4);
        const float mk = -1.4426950408889634e9f;
        Ms[t * 4 + 0] = mv.x * mk;
        Ms[t * 4 + 1] = mv.y * mk;
        Ms[t * 4 + 2] = mv.z * mk;
        Ms[t * 4 + 3] = mv.w * mk;
    }

    i32x4 aq[2][2];   // [q-group][k-half]
    #pragma unroll
    for (int g = 0; g < 2; ++g) {
        aq[g][0] = *reinterpret_cast<const i32x4*>(&Qp[(qw + g * 16 + lr) * DEPTH + lg * 8]);
        aq[g][1] = *reinterpret_cast<const i32x4*>(&Qp[(qw + g * 16 + lr) * DEPTH + 32 + lg * 8]);
    }

    f32x4 ctx[2][4];
    #pragma unroll
    for (int g = 0; g < 2; ++g)
        #pragma unroll
        for (int i = 0; i < 4; ++i) ctx[g][i] = f32x4{0.f, 0.f, 0.f, 0.f};
    float psum[2] = {0.f, 0.f};

    // staging geometry: row r0 (0..31), 16B slot c8 (0..7), swizzle slot ^= row&7
    const int r0 = t >> 3;
    const int c8 = t & 7;
    const int swz0 = (c8 ^ (r0 & 7)) * 8;   // (r0+32)&7 == r0&7
    u16* kd0 = Ks  + r0 * 64 + swz0;
    u16* kd1 = Ks  + (r0 + 32) * 64 + swz0;
    u16* vd0 = Vts + r0 * 64 + swz0;
    u16* vd1 = Vts + (r0 + 32) * 64 + swz0;
    const u16* ksrc0 = Kp + r0 * DEPTH + c8 * 8;
    const u16* ksrc1 = Kp + (r0 + 32) * DEPTH + c8 * 8;
    const u16* vsrc0 = Vp + r0 * SEQ + c8 * 8;
    const u16* vsrc1 = Vp + (r0 + 32) * SEQ + c8 * 8;
    u16* PsW = Ps[w];

    // loop-invariant P-store pointers: row q = g*16+lr, k-cols tt*16 + lg*4 .. +3
    u16* pdst[2][4];
    #pragma unroll
    for (int g = 0; g < 2; ++g)
        #pragma unroll
        for (int tt = 0; tt < 4; ++tt) {
            int slot = tt * 2 + (lg >> 1);
            pdst[g][tt] = PsW + (g * 16 + lr) * 64 + ((slot ^ (lr & 7)) << 3) + ((lg & 1) << 2);
        }

    // T14: prime first tile into registers
    uint4 kr0 = *reinterpret_cast<const uint4*>(ksrc0);
    uint4 kr1 = *reinterpret_cast<const uint4*>(ksrc1);
    uint4 vr0 = *reinterpret_cast<const uint4*>(vsrc0);
    uint4 vr1 = *reinterpret_cast<const uint4*>(vsrc1);

    for (int kt = 0; kt < SEQ; kt += 64) {
        __syncthreads();   // previous tile's compute done; LDS free
        *reinterpret_cast<uint4*>(kd0) = kr0;
        *reinterpret_cast<uint4*>(kd1) = kr1;
        *reinterpret_cast<uint4*>(vd0) = vr0;
        *reinterpret_cast<uint4*>(vd1) = vr1;
        if (kt + 64 < SEQ) {   // issue next tile's loads; complete under compute
            int kn = kt + 64;
            kr0 = *reinterpret_cast<const uint4*>(ksrc0 + kn * DEPTH);
            kr1 = *reinterpret_cast<const uint4*>(ksrc1 + kn * DEPTH);
            vr0 = *reinterpret_cast<const uint4*>(vsrc0 + kn);
            vr1 = *reinterpret_cast<const uint4*>(vsrc1 + kn);
        }
        __syncthreads();

        // QK^T, swapped operands: lane holds q = g*16+lr, k = tt*16+lg*4+r
        f32x4 sc[2][4];
        #pragma unroll
        for (int g = 0; g < 2; ++g)
            #pragma unroll
            for (int i = 0; i < 4; ++i) sc[g][i] = f32x4{0.f, 0.f, 0.f, 0.f};
        __builtin_amdgcn_s_setprio(1);
        #pragma unroll
        for (int tt = 0; tt < 4; ++tt) {
            int row = tt * 16 + lr, rs = row & 7;
            const u16* kr = Ks + row * 64;
            i32x4 bk0 = *reinterpret_cast<const i32x4*>(kr + ((lg ^ rs) << 3));
            i32x4 bk1 = *reinterpret_cast<const i32x4*>(kr + (((4 + lg) ^ rs) << 3));
            mfma_bf16(sc[0][tt], bk0, aq[0][0]);
            mfma_bf16(sc[0][tt], bk1, aq[0][1]);
            mfma_bf16(sc[1][tt], bk0, aq[1][0]);
            mfma_bf16(sc[1][tt], bk1, aq[1][1]);
        }
        __builtin_amdgcn_s_setprio(0);
        asm volatile("s_nop 7\n\ts_nop 7");

        #pragma unroll
        for (int tt = 0; tt < 4; ++tt) {
            float4 m4 = *reinterpret_cast<const float4*>(&Ms[kt + tt * 16 + lg * 4]);
            #pragma unroll
            for (int g = 0; g < 2; ++g) {
                float p0 = __builtin_amdgcn_exp2f(sc[g][tt][0] + m4.x);
                float p1 = __builtin_amdgcn_exp2f(sc[g][tt][1] + m4.y);
                float p2 = __builtin_amdgcn_exp2f(sc[g][tt][2] + m4.z);
                float p3 = __builtin_amdgcn_exp2f(sc[g][tt][3] + m4.w);
                psum[g] += (p0 + p1) + (p2 + p3);
                uint2 u;
                u.x = cvt_pk_bf16(p0, p1);
                u.y = cvt_pk_bf16(p2, p3);
                *reinterpret_cast<uint2*>(pdst[g][tt]) = u;
            }
        }

        // PV: ctx[g](16q x 64d) += P[g](16q x 64k) @ V(64k x 64d); bv shared across groups
        const int rswz = lr & 7;
        i32x4 pa[2][2];
        #pragma unroll
        for (int g = 0; g < 2; ++g) {
            const u16* pr = PsW + (g * 16 + lr) * 64;
            pa[g][0] = *reinterpret_cast<const i32x4*>(pr + ((lg ^ rswz) << 3));
            pa[g][1] = *reinterpret_cast<const i32x4*>(pr + (((4 + lg) ^ rswz) << 3));
        }
        __builtin_amdgcn_s_setprio(1);
        #pragma unroll
        for (int dt = 0; dt < 4; ++dt) {
            int dcol = dt * 16 + lr, ds = dcol & 7;
            const u16* vr = Vts + dcol * 64;
            i32x4 bv0 = *reinterpret_cast<const i32x4*>(vr + ((lg ^ ds) << 3));
            i32x4 bv1 = *reinterpret_cast<const i32x4*>(vr + (((4 + lg) ^ ds) << 3));
            mfma_bf16(ctx[0][dt], pa[0][0], bv0);
            mfma_bf16(ctx[0][dt], pa[0][1], bv1);
            mfma_bf16(ctx[1][dt], pa[1][0], bv0);
            mfma_bf16(ctx[1][dt], pa[1][1], bv1);
        }
        __builtin_amdgcn_s_setprio(0);
    }
    asm volatile("s_nop 7\n\ts_nop 7");
    #pragma unroll
    for (int g = 0; g < 2; ++g) {
        psum[g] += __shfl_xor(psum[g], 16);
        psum[g] += __shfl_xor(psum[g], 32);
    }
    float inv0 = 1.f / psum[0];
    float inv1 = 1.f / psum[1];
    // in-place ctx write over this wave's own Q rows (head layout)
    #pragma unroll
    for (int g = 0; g < 2; ++g) {
        float invr[4];
        #pragma unroll
        for (int r = 0; r < 4; ++r)
            invr[r] = __shfl(g ? inv1 : inv0, lg * 4 + r);   // ctx rows q = g*16 + lg*4 + r
        #pragma unroll
        for (int dt = 0; dt < 4; ++dt)
            #pragma unroll
            for (int r = 0; r < 4; ++r) {
                int s = qw + g * 16 + lg * 4 + r;
                int d = dt * 16 + lr;
                Qp[s * DEPTH + d] = f2bf(ctx[g][dt][r] * invr[r]);
            }
    }
}

// ---------------- output projection (r15-proven, verbatim: 2-phase, all-gload) ----------------
__global__ __launch_bounds__(256) void outproj_kernel(
    const u16* __restrict__ Xbq, const u16* __restrict__ CTXh,
    const u16* __restrict__ Wto,  // bf16 (1024 n x 2048 k)
    const float* __restrict__ Bo, float* __restrict__ Out)
{
    __shared__ u16 As[2][128 * 64];
    __shared__ u16 Bs[2][128 * 64];

    const int t = threadIdx.x;
    const int m0 = blockIdx.x * 128, n0 = blockIdx.y * 128;
    const int lane = t & 63, w = t >> 6;
    const int wu = __builtin_amdgcn_readfirstlane(w);
    const int wm = w >> 1, wn = w & 1;
    const int lr = lane & 15, lg = lane >> 4;
    const int srow = lane >> 3;                              // 8 rows per gload
    const int scol = ((lane & 7) ^ (srow & 7)) * 8;          // pre-swizzled source slot

    const int rowslab = m0 + wu * 32;                        // slab base row
    const int bb = rowslab >> 10, sr = rowslab & 1023;       // batch, seq base
    const u16* gaq = Xbq + (rowslab + srow) * DMODEL + scol;
    const u16* gb  = Wto + (n0 + wu * 32 + srow) * (2 * DMODEL) + scol;

    f32x4 acc[4][4];
    #pragma unroll
    for (int i = 0; i < 4; ++i)
        #pragma unroll
        for (int j = 0; j < 4; ++j) acc[i][j] = f32x4{0.f, 0.f, 0.f, 0.f};

    auto STAGE = [&](int buf, int k0) {
        u16* la = As[buf] + wu * 32 * 64;
        u16* lb = Bs[buf] + wu * 32 * 64;
        gload16(gb + k0,                   lb);
        gload16(gb + k0 +  8 * 2 * DMODEL, lb +  8 * 64);   // row += 8: row&7 unchanged
        gload16(gb + k0 + 16 * 2 * DMODEL, lb + 16 * 64);
        gload16(gb + k0 + 24 * 2 * DMODEL, lb + 24 * 64);
        const u16* ga;
        int rstride;
        if (k0 < DMODEL) {
            ga = gaq + k0;
            rstride = DMODEL;
        } else {
            int h = (k0 - DMODEL) >> 6;
            ga = CTXh + (((bb << 4) + h) * SEQ + sr + srow) * DEPTH + scol;
            rstride = DEPTH;
        }
        gload16(ga,                la);
        gload16(ga +  8 * rstride, la +  8 * 64);
        gload16(ga + 16 * rstride, la + 16 * 64);
        gload16(ga + 24 * rstride, la + 24 * 64);
    };

    STAGE(0, 0);
    __syncthreads();   // drain prologue stage
    for (int ts = 0; ts < 32; ++ts) {
        if (ts < 31) STAGE((ts + 1) & 1, (ts + 1) * 64);   // issue next tile early
        const int cur = ts & 1;
        const u16* Ac = As[cur];
        const u16* Bc = Bs[cur];
        #pragma unroll
        for (int kk = 0; kk < 2; ++kk) {
            const int pslot = ((kk * 4 + lg) ^ (lr & 7)) << 3;   // swizzled read slot
            i32x4 af[4], bfr[4];
            #pragma unroll
            for (int mi = 0; mi < 4; ++mi)
                af[mi] = *reinterpret_cast<const i32x4*>(
                    &Ac[(wm * 64 + mi * 16 + lr) * 64 + pslot]);
            #pragma unroll
            for (int ni = 0; ni < 4; ++ni)
                bfr[ni] = *reinterpret_cast<const i32x4*>(
                    &Bc[(wn * 64 + ni * 16 + lr) * 64 + pslot]);
            #pragma unroll
            for (int mi = 0; mi < 4; ++mi)
                #pragma unroll
                for (int ni = 0; ni < 4; ++ni)
                    mfma_bf16(acc[mi][ni], af[mi], bfr[ni]);
        }
        __syncthreads();   // drains stage(ts+1) loads (flew during compute)
    }
    asm volatile("s_nop 7\n\ts_nop 7");
    #pragma unroll
    for (int mi = 0; mi < 4; ++mi)
        #pragma unroll
        for (int ni = 0; ni < 4; ++ni) {
            int n = n0 + wn * 64 + ni * 16 + lr;
            float bv = Bo[n];
            #pragma unroll
            for (int r = 0; r < 4; ++r) {
                int m = m0 + wm * 64 + mi * 16 + lg * 4 + r;
                Out[m * DMODEL + n] = acc[mi][ni][r] + bv;
            }
        }
}

extern "C" void kernel_launch(void* const* d_in, const int* in_sizes, int n_in,
                              void* d_out, int out_size, void* d_ws, size_t ws_size,
                              hipStream_t stream) {
    const float* v    = (const float*)d_in[0];
    const float* k    = (const float*)d_in[1];
    const float* q_in = (const float*)d_in[2];
    const float* mask = (const float*)d_in[3];
    const float* wq_w = (const float*)d_in[4];
    const float* wq_b = (const float*)d_in[5];
    const float* wk_w = (const float*)d_in[6];
    const float* wk_b = (const float*)d_in[7];
    const float* wv_w = (const float*)d_in[8];
    const float* wv_b = (const float*)d_in[9];
    const float* wo_w = (const float*)d_in[10];
    const float* wo_b = (const float*)d_in[11];
    float* out = (float*)d_out;

    // proven 74 MB workspace layout
    u16* ws  = (u16*)d_ws;
    u16* Wtq = ws;                  // 1M u16
    u16* Wtk = Wtq + (1u << 20);
    u16* Wtv = Wtk + (1u << 20);
    u16* Wto = Wtv + (1u << 20);    // 2M u16
    u16* Qh  = Wto + (2u << 20);    // 8M u16 each: Qh -> ctx in-place
    u16* Kh  = Qh + (8u << 20);
    u16* Vt  = Kh + (8u << 20);     // transposed (B,H,64,S)
    u16* Xbq = Vt + (8u << 20);     // bf16 q_in, live until outproj

    // bf16 k/v scratch in d_out (dead before outproj writes out)
    u16* Xbk = (u16*)d_out;
    u16* Xbv = (u16*)d_out + (8u << 20);

    cvt_kernel<<<dim3(4096, 3), 256, 0, stream>>>(q_in, k, v, Xbq, Xbk, Xbv);

    transpose_cvt_all<<<dim3(32, 64, 4), 256, 0, stream>>>(
        wq_w, wk_w, wv_w, wo_w, Wtq, Wtk, Wtv, Wto);

    proj_kernel<<<dim3(64, 8, 3), 256, 0, stream>>>(
        Xbq, Xbk, Xbv, Wtq, Wtk, Wtv, wq_b, wk_b, wv_b, Qh, Kh, Vt);

    attn_kernel<<<dim3(8, 128), 256, 0, stream>>>(Qh, Kh, Vt, mask);

    outproj_kernel<<<dim3(64, 8), 256, 0, stream>>>(Xbq, Qh, Wto, wo_b, out);
}

// Round 18
// 171.852 us; speedup vs baseline: 1.0898x; 1.0138x over previous
//
#include <hip/hip_runtime.h>

#define NHEADS 16
#define DEPTH  64
#define BATCH  8
#define SEQ    1024
#define DMODEL 1024
#define MTOT   (BATCH*SEQ)   // 8192

typedef float f32x4 __attribute__((ext_vector_type(4)));
typedef int   i32x4 __attribute__((ext_vector_type(4)));
typedef unsigned short u16;

static __device__ inline u16 f2bf(float x) {
    unsigned int u = __builtin_bit_cast(unsigned int, x);
    u += 0x7FFFu + ((u >> 16) & 1u);   // RNE
    return (u16)(u >> 16);
}

// pack 2 f32 -> 2 bf16 (RNE), one instruction; lo -> low 16 bits (r10-proven)
static __device__ inline unsigned cvt_pk_bf16(float lo, float hi) {
    unsigned r;
    asm("v_cvt_pk_bf16_f32 %0, %1, %2" : "=v"(r) : "v"(lo), "v"(hi));
    return r;
}

// D = A(16x32, bf16) * B(32x16, bf16) + D, fp32 acc.
// A frag: lane holds A[l&15][8*(l>>4)+i] ; B frag: B[8*(l>>4)+i][l&15]
// C/D:    lane,reg r -> D[(l>>4)*4 + r][l&15]
static __device__ inline void mfma_bf16(f32x4& acc, i32x4 a, i32x4 b) {
    asm("v_mfma_f32_16x16x32_bf16 %0, %1, %2, %0" : "+v"(acc) : "v"(a), "v"(b));
}

// async global->LDS, 16B/lane; lds dest is wave-uniform base (+ lane*16 by HW)
static __device__ inline void gload16(const u16* g, u16* l) {
    __builtin_amdgcn_global_load_lds(
        (const __attribute__((address_space(1))) void*)g,
        (__attribute__((address_space(3))) void*)l,
        16, 0, 0);
}

// ---------------- pre-pass: weight transpose+cvt (z 0..3) + activation cvt (z 4..6) ----------------
__global__ __launch_bounds__(256) void prepass_kernel(
    const float* __restrict__ Wq, const float* __restrict__ Wk,
    const float* __restrict__ Wv, const float* __restrict__ Wo,
    u16* __restrict__ Wtq, u16* __restrict__ Wtk,
    u16* __restrict__ Wtv, u16* __restrict__ Wto,
    const float* __restrict__ Aq, const float* __restrict__ Ak, const float* __restrict__ Av,
    u16* __restrict__ Xbq, u16* __restrict__ Xbk, u16* __restrict__ Xbv)
{
    const int z = blockIdx.z;
    if (z >= 4) {
        // streaming fp32 -> bf16: 2048 blocks x 256 threads x 16 elements = 8M
        const float* src = (z == 4) ? Aq : (z == 5) ? Ak : Av;
        u16* dst         = (z == 4) ? Xbq : (z == 5) ? Xbk : Xbv;
        int i = ((blockIdx.y * 32 + blockIdx.x) * 256 + threadIdx.x) * 16;
        #pragma unroll
        for (int h = 0; h < 2; ++h) {
            float4 f0 = *reinterpret_cast<const float4*>(src + i + h * 8);
            float4 f1 = *reinterpret_cast<const float4*>(src + i + h * 8 + 4);
            uint4 u;
            u.x = cvt_pk_bf16(f0.x, f0.y);
            u.y = cvt_pk_bf16(f0.z, f0.w);
            u.z = cvt_pk_bf16(f1.x, f1.y);
            u.w = cvt_pk_bf16(f1.z, f1.w);
            *reinterpret_cast<uint4*>(dst + i + h * 8) = u;
        }
        return;
    }
    if (z < 3 && blockIdx.y >= 32) return;
    const float* W = (z == 0) ? Wq : (z == 1) ? Wk : (z == 2) ? Wv : Wo;
    u16* Wt        = (z == 0) ? Wtq : (z == 1) ? Wtk : (z == 2) ? Wtv : Wto;
    const int K = (z == 3) ? 2048 : 1024;
    const int N = 1024;

    __shared__ u16 tile[32][33];
    int n0 = blockIdx.x * 32, k0 = blockIdx.y * 32;
    int tx = threadIdx.x & 31, ty = threadIdx.x >> 5;   // 32 x 8
    #pragma unroll
    for (int r = 0; r < 32; r += 8)
        tile[r + ty][tx] = f2bf(W[(k0 + r + ty) * N + n0 + tx]);
    __syncthreads();
    #pragma unroll
    for (int r = 0; r < 32; r += 8)
        Wt[(n0 + r + ty) * K + k0 + tx] = tile[tx][r + ty];
}

// ---------------- QKV projection (r15/r17-proven: single-buffer BK=64, source-swizzled LDS) ----------------
__global__ __launch_bounds__(256) void proj_kernel(
    const u16* __restrict__ Xq, const u16* __restrict__ Xk, const u16* __restrict__ Xv,
    const u16* __restrict__ Wtq, const u16* __restrict__ Wtk, const u16* __restrict__ Wtv,
    const float* __restrict__ Bq, const float* __restrict__ Bk, const float* __restrict__ Bv,
    u16* __restrict__ Qh, u16* __restrict__ Kh, u16* __restrict__ Vt)
{
    const int z = blockIdx.z;
    const u16* X    = (z == 0) ? Xq  : (z == 1) ? Xk  : Xv;
    const u16* Wt   = (z == 0) ? Wtq : (z == 1) ? Wtk : Wtv;
    const float* Bi = (z == 0) ? Bq  : (z == 1) ? Bk  : Bv;
    u16* Out        = (z == 0) ? Qh  : (z == 1) ? Kh  : Vt;

    __shared__ u16 As[128 * 64];
    __shared__ u16 Bs[128 * 64];

    const int t = threadIdx.x;
    const int m0 = blockIdx.x * 128, n0 = blockIdx.y * 128;
    const int lane = t & 63, w = t >> 6;
    const int wu = __builtin_amdgcn_readfirstlane(w);
    const int wm = w >> 1, wn = w & 1;
    const int lr = lane & 15, lg = lane >> 4;
    const int srow = lane >> 3;                              // 8 rows per gload
    const int scol = ((lane & 7) ^ (srow & 7)) * 8;          // pre-swizzled source slot

    const u16* ga = X  + (m0 + wu * 32 + srow) * DMODEL + scol;
    const u16* gb = Wt + (n0 + wu * 32 + srow) * DMODEL + scol;
    u16* la = As + wu * 32 * 64;
    u16* lb = Bs + wu * 32 * 64;

    f32x4 acc[4][4];
    #pragma unroll
    for (int i = 0; i < 4; ++i)
        #pragma unroll
        for (int j = 0; j < 4; ++j) acc[i][j] = f32x4{0.f, 0.f, 0.f, 0.f};

    for (int k0 = 0; k0 < DMODEL; k0 += 64) {
        __syncthreads();
        gload16(ga + k0,               la);
        gload16(ga + k0 +  8 * DMODEL, la +  8 * 64);   // row += 8: row&7 unchanged
        gload16(ga + k0 + 16 * DMODEL, la + 16 * 64);
        gload16(ga + k0 + 24 * DMODEL, la + 24 * 64);
        gload16(gb + k0,               lb);
        gload16(gb + k0 +  8 * DMODEL, lb +  8 * 64);
        gload16(gb + k0 + 16 * DMODEL, lb + 16 * 64);
        gload16(gb + k0 + 24 * DMODEL, lb + 24 * 64);
        __syncthreads();
        #pragma unroll
        for (int kk = 0; kk < 2; ++kk) {
            const int pslot = ((kk * 4 + lg) ^ (lr & 7)) << 3;   // swizzled read slot
            i32x4 af[4], bfr[4];
            #pragma unroll
            for (int mi = 0; mi < 4; ++mi)
                af[mi] = *reinterpret_cast<const i32x4*>(
                    &As[(wm * 64 + mi * 16 + lr) * 64 + pslot]);
            #pragma unroll
            for (int ni = 0; ni < 4; ++ni)
                bfr[ni] = *reinterpret_cast<const i32x4*>(
                    &Bs[(wn * 64 + ni * 16 + lr) * 64 + pslot]);
            #pragma unroll
            for (int mi = 0; mi < 4; ++mi)
                #pragma unroll
                for (int ni = 0; ni < 4; ++ni)
                    mfma_bf16(acc[mi][ni], af[mi], bfr[ni]);
        }
    }
    asm volatile("s_nop 7\n\ts_nop 7");
    #pragma unroll
    for (int mi = 0; mi < 4; ++mi)
        #pragma unroll
        for (int ni = 0; ni < 4; ++ni) {
            int n = n0 + wn * 64 + ni * 16 + lr;
            float bv = Bi[n];
            int h = n >> 6, d = n & 63;
            int mb = m0 + wm * 64 + mi * 16 + lg * 4;
            int b = mb >> 10, srw = mb & 1023;
            if (z == 2) {
                uint2 u;
                u.x = cvt_pk_bf16(acc[mi][ni][0] + bv, acc[mi][ni][1] + bv);
                u.y = cvt_pk_bf16(acc[mi][ni][2] + bv, acc[mi][ni][3] + bv);
                *reinterpret_cast<uint2*>(&Vt[(((b << 4) + h) * DEPTH + d) * SEQ + srw]) = u;
            } else if (z == 0) {
                // 0.125 (1/sqrt(64)) * log2(e): scores come out of QK^T in exp2 domain
                #pragma unroll
                for (int r = 0; r < 4; ++r)
                    Out[(((b << 4) + h) * SEQ + srw + r) * DEPTH + d] = f2bf((acc[mi][ni][r] + bv) * 0.18033688f);
            } else {
                #pragma unroll
                for (int r = 0; r < 4; ++r)
                    Out[(((b << 4) + h) * SEQ + srw + r) * DEPTH + d] = f2bf(acc[mi][ni][r] + bv);
            }
        }
}

// ---------------- flash attention (r17-proven; XCD-local grid: x = bh, y = qblk) ----------------
// Same-bh blocks get linear ids differing by gridDim.x (=128 ≡ 0 mod 8) -> same XCD
// -> that bh's K/V (256 KB) stays in the XCD's 4 MB L2 across all 8 q-blocks.
__global__ __launch_bounds__(256) void attn_kernel(
    u16* __restrict__ Qh, const u16* __restrict__ Kh, const u16* __restrict__ Vt,
    const float* __restrict__ mask)
{
    __shared__ u16 Ks[64 * 64];
    __shared__ u16 Vts[64 * 64];     // [d][k]
    __shared__ u16 Ps[4][32 * 64];   // per-wave [32 q][64 k], swizzled cols
    __shared__ float Ms[SEQ];

    const int t = threadIdx.x;
    const int lane = t & 63, w = t >> 6;
    const int lr = lane & 15, lg = lane >> 4;
    const int bh = blockIdx.x;                  // XCD-local: bh on x
    const int b = bh >> 4;
    const int qw = blockIdx.y * 128 + w * 32;   // this wave's 32 q rows

    u16* Qp       = Qh + bh * (SEQ * DEPTH);
    const u16* Kp = Kh + bh * (SEQ * DEPTH);
    const u16* Vp = Vt + bh * (SEQ * DEPTH);   // [d][s]

    // stage mask * (-1e9 * log2e) once (visible after first loop barrier)
    {
        float4 mv = *reinterpret_cast<const float4*>(mask + b * SEQ + t * 4);
        const float mk = -1.4426950408889634e9f;
        Ms[t * 4 + 0] = mv.x * mk;
        Ms[t * 4 + 1] = mv.y * mk;
        Ms[t * 4 + 2] = mv.z * mk;
        Ms[t * 4 + 3] = mv.w * mk;
    }

    i32x4 aq[2][2];   // [q-group][k-half]
    #pragma unroll
    for (int g = 0; g < 2; ++g) {
        aq[g][0] = *reinterpret_cast<const i32x4*>(&Qp[(qw + g * 16 + lr) * DEPTH + lg * 8]);
        aq[g][1] = *reinterpret_cast<const i32x4*>(&Qp[(qw + g * 16 + lr) * DEPTH + 32 + lg * 8]);
    }

    f32x4 ctx[2][4];
    #pragma unroll
    for (int g = 0; g < 2; ++g)
        #pragma unroll
        for (int i = 0; i < 4; ++i) ctx[g][i] = f32x4{0.f, 0.f, 0.f, 0.f};
    float psum[2] = {0.f, 0.f};

    // staging geometry: row r0 (0..31), 16B slot c8 (0..7), swizzle slot ^= row&7
    const int r0 = t >> 3;
    const int c8 = t & 7;
    const int swz0 = (c8 ^ (r0 & 7)) * 8;   // (r0+32)&7 == r0&7
    u16* kd0 = Ks  + r0 * 64 + swz0;
    u16* kd1 = Ks  + (r0 + 32) * 64 + swz0;
    u16* vd0 = Vts + r0 * 64 + swz0;
    u16* vd1 = Vts + (r0 + 32) * 64 + swz0;
    const u16* ksrc0 = Kp + r0 * DEPTH + c8 * 8;
    const u16* ksrc1 = Kp + (r0 + 32) * DEPTH + c8 * 8;
    const u16* vsrc0 = Vp + r0 * SEQ + c8 * 8;
    const u16* vsrc1 = Vp + (r0 + 32) * SEQ + c8 * 8;
    u16* PsW = Ps[w];

    // loop-invariant P-store pointers: row q = g*16+lr, k-cols tt*16 + lg*4 .. +3
    u16* pdst[2][4];
    #pragma unroll
    for (int g = 0; g < 2; ++g)
        #pragma unroll
        for (int tt = 0; tt < 4; ++tt) {
            int slot = tt * 2 + (lg >> 1);
            pdst[g][tt] = PsW + (g * 16 + lr) * 64 + ((slot ^ (lr & 7)) << 3) + ((lg & 1) << 2);
        }

    // T14: prime first tile into registers
    uint4 kr0 = *reinterpret_cast<const uint4*>(ksrc0);
    uint4 kr1 = *reinterpret_cast<const uint4*>(ksrc1);
    uint4 vr0 = *reinterpret_cast<const uint4*>(vsrc0);
    uint4 vr1 = *reinterpret_cast<const uint4*>(vsrc1);

    for (int kt = 0; kt < SEQ; kt += 64) {
        __syncthreads();   // previous tile's compute done; LDS free
        *reinterpret_cast<uint4*>(kd0) = kr0;
        *reinterpret_cast<uint4*>(kd1) = kr1;
        *reinterpret_cast<uint4*>(vd0) = vr0;
        *reinterpret_cast<uint4*>(vd1) = vr1;
        if (kt + 64 < SEQ) {   // issue next tile's loads; complete under compute
            int kn = kt + 64;
            kr0 = *reinterpret_cast<const uint4*>(ksrc0 + kn * DEPTH);
            kr1 = *reinterpret_cast<const uint4*>(ksrc1 + kn * DEPTH);
            vr0 = *reinterpret_cast<const uint4*>(vsrc0 + kn);
            vr1 = *reinterpret_cast<const uint4*>(vsrc1 + kn);
        }
        __syncthreads();

        // QK^T, swapped operands: lane holds q = g*16+lr, k = tt*16+lg*4+r
        f32x4 sc[2][4];
        #pragma unroll
        for (int g = 0; g < 2; ++g)
            #pragma unroll
            for (int i = 0; i < 4; ++i) sc[g][i] = f32x4{0.f, 0.f, 0.f, 0.f};
        __builtin_amdgcn_s_setprio(1);
        #pragma unroll
        for (int tt = 0; tt < 4; ++tt) {
            int row = tt * 16 + lr, rs = row & 7;
            const u16* kr = Ks + row * 64;
            i32x4 bk0 = *reinterpret_cast<const i32x4*>(kr + ((lg ^ rs) << 3));
            i32x4 bk1 = *reinterpret_cast<const i32x4*>(kr + (((4 + lg) ^ rs) << 3));
            mfma_bf16(sc[0][tt], bk0, aq[0][0]);
            mfma_bf16(sc[0][tt], bk1, aq[0][1]);
            mfma_bf16(sc[1][tt], bk0, aq[1][0]);
            mfma_bf16(sc[1][tt], bk1, aq[1][1]);
        }
        __builtin_amdgcn_s_setprio(0);
        asm volatile("s_nop 7\n\ts_nop 7");

        #pragma unroll
        for (int tt = 0; tt < 4; ++tt) {
            float4 m4 = *reinterpret_cast<const float4*>(&Ms[kt + tt * 16 + lg * 4]);
            #pragma unroll
            for (int g = 0; g < 2; ++g) {
                float p0 = __builtin_amdgcn_exp2f(sc[g][tt][0] + m4.x);
                float p1 = __builtin_amdgcn_exp2f(sc[g][tt][1] + m4.y);
                float p2 = __builtin_amdgcn_exp2f(sc[g][tt][2] + m4.z);
                float p3 = __builtin_amdgcn_exp2f(sc[g][tt][3] + m4.w);
                psum[g] += (p0 + p1) + (p2 + p3);
                uint2 u;
                u.x = cvt_pk_bf16(p0, p1);
                u.y = cvt_pk_bf16(p2, p3);
                *reinterpret_cast<uint2*>(pdst[g][tt]) = u;
            }
        }

        // PV: ctx[g](16q x 64d) += P[g](16q x 64k) @ V(64k x 64d); bv shared across groups
        const int rswz = lr & 7;
        i32x4 pa[2][2];
        #pragma unroll
        for (int g = 0; g < 2; ++g) {
            const u16* pr = PsW + (g * 16 + lr) * 64;
            pa[g][0] = *reinterpret_cast<const i32x4*>(pr + ((lg ^ rswz) << 3));
            pa[g][1] = *reinterpret_cast<const i32x4*>(pr + (((4 + lg) ^ rswz) << 3));
        }
        __builtin_amdgcn_s_setprio(1);
        #pragma unroll
        for (int dt = 0; dt < 4; ++dt) {
            int dcol = dt * 16 + lr, ds = dcol & 7;
            const u16* vr = Vts + dcol * 64;
            i32x4 bv0 = *reinterpret_cast<const i32x4*>(vr + ((lg ^ ds) << 3));
            i32x4 bv1 = *reinterpret_cast<const i32x4*>(vr + (((4 + lg) ^ ds) << 3));
            mfma_bf16(ctx[0][dt], pa[0][0], bv0);
            mfma_bf16(ctx[0][dt], pa[0][1], bv1);
            mfma_bf16(ctx[1][dt], pa[1][0], bv0);
            mfma_bf16(ctx[1][dt], pa[1][1], bv1);
        }
        __builtin_amdgcn_s_setprio(0);
    }
    asm volatile("s_nop 7\n\ts_nop 7");
    #pragma unroll
    for (int g = 0; g < 2; ++g) {
        psum[g] += __shfl_xor(psum[g], 16);
        psum[g] += __shfl_xor(psum[g], 32);
    }
    float inv0 = 1.f / psum[0];
    float inv1 = 1.f / psum[1];
    // in-place ctx write over this wave's own Q rows (head layout)
    #pragma unroll
    for (int g = 0; g < 2; ++g) {
        float invr[4];
        #pragma unroll
        for (int r = 0; r < 4; ++r)
            invr[r] = __shfl(g ? inv1 : inv0, lg * 4 + r);   // ctx rows q = g*16 + lg*4 + r
        #pragma unroll
        for (int dt = 0; dt < 4; ++dt)
            #pragma unroll
            for (int r = 0; r < 4; ++r) {
                int s = qw + g * 16 + lg * 4 + r;
                int d = dt * 16 + lr;
                Qp[s * DEPTH + d] = f2bf(ctx[g][dt][r] * invr[r]);
            }
    }
}

// ---------------- output projection (r15/r17-proven, verbatim: 2-phase, all-gload) ----------------
__global__ __launch_bounds__(256) void outproj_kernel(
    const u16* __restrict__ Xbq, const u16* __restrict__ CTXh,
    const u16* __restrict__ Wto,  // bf16 (1024 n x 2048 k)
    const float* __restrict__ Bo, float* __restrict__ Out)
{
    __shared__ u16 As[2][128 * 64];
    __shared__ u16 Bs[2][128 * 64];

    const int t = threadIdx.x;
    const int m0 = blockIdx.x * 128, n0 = blockIdx.y * 128;
    const int lane = t & 63, w = t >> 6;
    const int wu = __builtin_amdgcn_readfirstlane(w);
    const int wm = w >> 1, wn = w & 1;
    const int lr = lane & 15, lg = lane >> 4;
    const int srow = lane >> 3;                              // 8 rows per gload
    const int scol = ((lane & 7) ^ (srow & 7)) * 8;          // pre-swizzled source slot

    const int rowslab = m0 + wu * 32;                        // slab base row
    const int bb = rowslab >> 10, sr = rowslab & 1023;       // batch, seq base
    const u16* gaq = Xbq + (rowslab + srow) * DMODEL + scol;
    const u16* gb  = Wto + (n0 + wu * 32 + srow) * (2 * DMODEL) + scol;

    f32x4 acc[4][4];
    #pragma unroll
    for (int i = 0; i < 4; ++i)
        #pragma unroll
        for (int j = 0; j < 4; ++j) acc[i][j] = f32x4{0.f, 0.f, 0.f, 0.f};

    auto STAGE = [&](int buf, int k0) {
        u16* la = As[buf] + wu * 32 * 64;
        u16* lb = Bs[buf] + wu * 32 * 64;
        gload16(gb + k0,                   lb);
        gload16(gb + k0 +  8 * 2 * DMODEL, lb +  8 * 64);   // row += 8: row&7 unchanged
        gload16(gb + k0 + 16 * 2 * DMODEL, lb + 16 * 64);
        gload16(gb + k0 + 24 * 2 * DMODEL, lb + 24 * 64);
        const u16* ga;
        int rstride;
        if (k0 < DMODEL) {
            ga = gaq + k0;
            rstride = DMODEL;
        } else {
            int h = (k0 - DMODEL) >> 6;
            ga = CTXh + (((bb << 4) + h) * SEQ + sr + srow) * DEPTH + scol;
            rstride = DEPTH;
        }
        gload16(ga,                la);
        gload16(ga +  8 * rstride, la +  8 * 64);
        gload16(ga + 16 * rstride, la + 16 * 64);
        gload16(ga + 24 * rstride, la + 24 * 64);
    };

    STAGE(0, 0);
    __syncthreads();   // drain prologue stage
    for (int ts = 0; ts < 32; ++ts) {
        if (ts < 31) STAGE((ts + 1) & 1, (ts + 1) * 64);   // issue next tile early
        const int cur = ts & 1;
        const u16* Ac = As[cur];
        const u16* Bc = Bs[cur];
        #pragma unroll
        for (int kk = 0; kk < 2; ++kk) {
            const int pslot = ((kk * 4 + lg) ^ (lr & 7)) << 3;   // swizzled read slot
            i32x4 af[4], bfr[4];
            #pragma unroll
            for (int mi = 0; mi < 4; ++mi)
                af[mi] = *reinterpret_cast<const i32x4*>(
                    &Ac[(wm * 64 + mi * 16 + lr) * 64 + pslot]);
            #pragma unroll
            for (int ni = 0; ni < 4; ++ni)
                bfr[ni] = *reinterpret_cast<const i32x4*>(
                    &Bc[(wn * 64 + ni * 16 + lr) * 64 + pslot]);
            #pragma unroll
            for (int mi = 0; mi < 4; ++mi)
                #pragma unroll
                for (int ni = 0; ni < 4; ++ni)
                    mfma_bf16(acc[mi][ni], af[mi], bfr[ni]);
        }
        __syncthreads();   // drains stage(ts+1) loads (flew during compute)
    }
    asm volatile("s_nop 7\n\ts_nop 7");
    #pragma unroll
    for (int mi = 0; mi < 4; ++mi)
        #pragma unroll
        for (int ni = 0; ni < 4; ++ni) {
            int n = n0 + wn * 64 + ni * 16 + lr;
            float bv = Bo[n];
            #pragma unroll
            for (int r = 0; r < 4; ++r) {
                int m = m0 + wm * 64 + mi * 16 + lg * 4 + r;
                Out[m * DMODEL + n] = acc[mi][ni][r] + bv;
            }
        }
}

extern "C" void kernel_launch(void* const* d_in, const int* in_sizes, int n_in,
                              void* d_out, int out_size, void* d_ws, size_t ws_size,
                              hipStream_t stream) {
    const float* v    = (const float*)d_in[0];
    const float* k    = (const float*)d_in[1];
    const float* q_in = (const float*)d_in[2];
    const float* mask = (const float*)d_in[3];
    const float* wq_w = (const float*)d_in[4];
    const float* wq_b = (const float*)d_in[5];
    const float* wk_w = (const float*)d_in[6];
    const float* wk_b = (const float*)d_in[7];
    const float* wv_w = (const float*)d_in[8];
    const float* wv_b = (const float*)d_in[9];
    const float* wo_w = (const float*)d_in[10];
    const float* wo_b = (const float*)d_in[11];
    float* out = (float*)d_out;

    // proven 74 MB workspace layout
    u16* ws  = (u16*)d_ws;
    u16* Wtq = ws;                  // 1M u16
    u16* Wtk = Wtq + (1u << 20);
    u16* Wtv = Wtk + (1u << 20);
    u16* Wto = Wtv + (1u << 20);    // 2M u16
    u16* Qh  = Wto + (2u << 20);    // 8M u16 each: Qh -> ctx in-place
    u16* Kh  = Qh + (8u << 20);
    u16* Vt  = Kh + (8u << 20);     // transposed (B,H,64,S)
    u16* Xbq = Vt + (8u << 20);     // bf16 q_in, live until outproj

    // bf16 k/v scratch in d_out (dead before outproj writes out)
    u16* Xbk = (u16*)d_out;
    u16* Xbv = (u16*)d_out + (8u << 20);

    prepass_kernel<<<dim3(32, 64, 7), 256, 0, stream>>>(
        wq_w, wk_w, wv_w, wo_w, Wtq, Wtk, Wtv, Wto,
        q_in, k, v, Xbq, Xbk, Xbv);

    proj_kernel<<<dim3(64, 8, 3), 256, 0, stream>>>(
        Xbq, Xbk, Xbv, Wtq, Wtk, Wtv, wq_b, wk_b, wv_b, Qh, Kh, Vt);

    attn_kernel<<<dim3(128, 8), 256, 0, stream>>>(Qh, Kh, Vt, mask);

    outproj_kernel<<<dim3(64, 8), 256, 0, stream>>>(Xbq, Qh, Wto, wo_b, out);
}